// Round 7
// baseline (15420.491 us; speedup 1.0000x reference)
//
#include <hip/hip_runtime.h>
#include <math.h>

// FWMemory: T=1024 sequential ticks, persistent-kernel design.
// R8: phase A full-column per-wave decomposition (c in registers).
// R10/R11: role separation by slack; weights in VGPRs; M in LDS.
// R12: epoch-tagged dataflow {f32,epoch} atoms; all barriers deleted.
// R13: shorten D's path-to-store + distribute err:
//  - D broadcasts only nvln (48 pairs) right after LN; out-matvec + HBM
//    write move off the critical path. err is recomputed by EVERY WG
//    (2 rows/thread, wcomb slice in 96 VGPRs, bitwise-identical order),
//    from zb=hwo+bcomb and labels staged in the tick-t tail.
//  - NC 144->48: one full M-row per C WG (9KB LDS), no chunk partials;
//    D big-spin 593->337 pairs.
//  - One dot per wave: B1 = WGs 56..116 (241 head dots), H = 117..255
//    (512 hWout dots, weights preloaded to VGPRs).
//  - D WGs skip the nvln spin (own LDS has it).

#define TT 1024
#define DD 2048
#define SS 1024
#define OO 512
#define MM 48
#define NG 4096
#define NWG 256
#define NTHR 256
#define NC 48        // C WGs: 0..47 (row w of M)
#define ND0 48       // D WGs: 48..55
#define NDE 56
#define NB0 56       // B1 WGs: 56..116 (slot = (w-56)*4+sc < 241)
#define NBE 117
#define NH0 117      // H WGs: 117..255 (hslot = (w-117)*4+sc < 512)
#define NSPIN 337    // 241 wr2 + 48 vp2 + 48 np2

// ---- ws layout (4-byte word offsets). Pairs are {val:u32, epoch:u32}. ----
#define W_HP2   0         // [1024 pairs] h
#define W_WR2   2048      // [256 pairs] head dots (tanh'd except slot 144)
#define W_VP2   2560      // [48 pairs] M@key per row
#define W_NP2   2656      // [48 pairs] M@rk per row
#define W_HW2   2752      // [512 pairs] h @ W_out
#define W_UD2   3776      // [48 pairs] beta*invg*delta
#define W_IVG2  3872      // [1 pair] invg
#define W_NV2   3874      // [48 pairs] nvln (LayerNorm'd readout vector)
#define ZERO_WORDS 208256
#define W_PRE    208256             // [1024*4096] precomputed gates
#define W_WWRT  (W_PRE + TT*NG)     // [241*1024] W_write|W_read transposed
#define W_WOUTT (W_WWRT + 241*SS)   // [512*1024] W_out transposed
#define W_WCOMB (W_WOUTT + OO*SS)   // [48*512]  W_rproj @ W_out
#define W_BCOMB (W_WCOMB + MM*OO)   // [512]     b_rproj @ W_out + b_out
#define W_WLRP  (W_BCOMB + OO)      // [256 WGs][4 s][1536 rows] float4(4 gates)

typedef unsigned long long u64;

__device__ __forceinline__ u64 ld64(const u64* p) {
  return __hip_atomic_load(p, __ATOMIC_RELAXED, __HIP_MEMORY_SCOPE_AGENT);
}
__device__ __forceinline__ void st64(u64* p, u64 v) {
  __hip_atomic_store(p, v, __ATOMIC_RELAXED, __HIP_MEMORY_SCOPE_AGENT);
}
__device__ __forceinline__ u64 mkpair(float v, int tag) {
  union { float f; unsigned u; } c; c.f = v;
  return (u64)c.u | ((u64)(unsigned)tag << 32);
}
__device__ __forceinline__ float pval(u64 p) {
  union { unsigned u; float f; } c; c.u = (unsigned)p; return c.f;
}
__device__ __forceinline__ int ptag(u64 p) { return (int)(unsigned)(p >> 32); }
__device__ __forceinline__ float spin1(const u64* p, int tag) {
  u64 q = ld64(p);
  while (ptag(q) != tag) { __builtin_amdgcn_s_sleep(1); q = ld64(p); }
  return pval(q);
}
__device__ __forceinline__ float sigm(float x) { return 1.f / (1.f + expf(-x)); }

// ---------------- one-time prep kernels ----------------

__global__ void build_wwrT(const float* __restrict__ Ww, const float* __restrict__ Wr,
                           float* __restrict__ wwrT) {
  int id = blockIdx.x * 256 + threadIdx.x;
  if (id < 241 * SS) {
    int d = id >> 10, s = id & 1023;
    wwrT[id] = (d < 145) ? Ww[s * 145 + d] : Wr[s * 96 + (d - 145)];
  }
}

__global__ void build_woutT(const float* __restrict__ Wo, float* __restrict__ woutT) {
  int id = blockIdx.x * 256 + threadIdx.x;  // 512*1024 exact
  int o = id >> 10, s = id & 1023;
  woutT[id] = Wo[s * OO + o];
}

// Full-column layout: dst[((s*1536)+l)*4+gb] = Wl[wrow(l)][gb*1024+s].
__global__ void repack_wl(const float* __restrict__ Wl, float* __restrict__ dst) {
  int id = blockIdx.x * 256 + threadIdx.x;  // 1024*1536*4 = 1536*NG exact
  int gb = id & 3;
  int r = id >> 2;
  int l = r % 1536;
  int s = r / 1536;
  int wrow = (l < 512) ? (2048 + l) : (2560 + l);
  dst[id] = Wl[(size_t)wrow * NG + gb * 1024 + s];
}

__global__ void wcomb_kernel(const float* __restrict__ Wrp, const float* __restrict__ brp,
                             const float* __restrict__ Wo, const float* __restrict__ bo,
                             float* __restrict__ wcomb, float* __restrict__ bcomb) {
  int id = blockIdx.x * 256 + threadIdx.x;  // 49*512 exact
  int a = id >> 9, o = id & 511;
  if (a < MM) {
    float acc = 0.f;
    for (int s = 0; s < SS; ++s) acc = fmaf(Wrp[a * SS + s], Wo[s * OO + o], acc);
    wcomb[a * OO + o] = acc;
  } else if (a == MM) {
    float acc = bo[o];
    for (int s = 0; s < SS; ++s) acc = fmaf(brp[s], Wo[s * OO + o], acc);
    bcomb[o] = acc;
  }
}

// pregates[t][j] = b_lstm[j] + inp[t] @ Wl[0:2048] + labels[t-1] @ Wl[2560:3072]
__global__ __launch_bounds__(256)
void pregate_gemm(const float* __restrict__ inp, const float* __restrict__ lab,
                  const float* __restrict__ Wl, const float* __restrict__ bl,
                  float* __restrict__ pre) {
  __shared__ float As[16][65];
  __shared__ float Bs[16][64];
  const int tid = threadIdx.x;
  const int j0 = blockIdx.x * 64;
  const int t0 = blockIdx.y * 64;
  const int tx = tid & 15, ty = tid >> 4;
  float acc[4][4] = {};
  for (int kc = 0; kc < 2560; kc += 16) {
    __syncthreads();
#pragma unroll
    for (int p = 0; p < 4; ++p) {
      int id = tid + p * 256;
      int r = id >> 4, kk = id & 15;
      int t = t0 + r, k = kc + kk;
      float v;
      if (k < DD) v = inp[(size_t)t * DD + k];
      else v = (t > 0) ? lab[(size_t)(t - 1) * OO + (k - DD)] : 0.f;
      As[kk][r] = v;
      int kr = id >> 6, j = id & 63;
      int k2 = kc + kr;
      int wrow = (k2 < DD) ? k2 : (512 + k2);  // 2560+(k2-2048)
      Bs[kr][j] = Wl[(size_t)wrow * NG + j0 + j];
    }
    __syncthreads();
#pragma unroll
    for (int kk = 0; kk < 16; ++kk) {
      float av[4], bv[4];
#pragma unroll
      for (int i = 0; i < 4; ++i) av[i] = As[kk][ty * 4 + i];
#pragma unroll
      for (int i = 0; i < 4; ++i) bv[i] = Bs[kk][tx * 4 + i];
#pragma unroll
      for (int i = 0; i < 4; ++i)
#pragma unroll
        for (int jx = 0; jx < 4; ++jx) acc[i][jx] = fmaf(av[i], bv[jx], acc[i][jx]);
    }
  }
#pragma unroll
  for (int i = 0; i < 4; ++i) {
    int t = t0 + ty * 4 + i;
#pragma unroll
    for (int jx = 0; jx < 4; ++jx) {
      int j = j0 + tx * 4 + jx;
      pre[(size_t)t * NG + j] = acc[i][jx] + bl[j];
    }
  }
}

// ---------------- persistent scan kernel ----------------

__global__ __launch_bounds__(NTHR, 1)
void persistent_kernel(float* ws, const float* __restrict__ labels,
                       const float* __restrict__ bwv, const float* __restrict__ brv,
                       float* __restrict__ out) {
  u64* const hp2 = (u64*)(ws + W_HP2);
  u64* const wr2 = (u64*)(ws + W_WR2);
  u64* const vp2 = (u64*)(ws + W_VP2);
  u64* const np2 = (u64*)(ws + W_NP2);
  u64* const hw2 = (u64*)(ws + W_HW2);
  u64* const ud2 = (u64*)(ws + W_UD2);
  u64* const iv2 = (u64*)(ws + W_IVG2);
  u64* const nv2 = (u64*)(ws + W_NV2);
  const float* const pre = ws + W_PRE;
  const float* const wwrT = ws + W_WWRT;
  const float* const woutT = ws + W_WOUTT;
  const float* const wcomb = ws + W_WCOMB;
  const float* const bcomb = ws + W_BCOMB;

  const int w = blockIdx.x;
  const int tid = threadIdx.x;
  const int sc = tid >> 6;   // wave id
  const int rl = tid & 63;   // lane
  const float4* const blk4 =
      (const float4*)(ws + W_WLRP) + (size_t)w * 6144 + (size_t)sc * 1536;

  const bool isC = (w < NC);
  const bool isD = (w >= ND0 && w < NDE);
  const int dbase = (w - ND0) * 64;

  // Constant gate weights -> registers.
  float4 werr[8], whh[16];
#pragma unroll
  for (int it = 0; it < 8; ++it) werr[it] = blk4[rl + it * 64];
#pragma unroll
  for (int it = 0; it < 16; ++it) whh[it] = blk4[512 + rl + it * 64];

  // wcomb slices for local err computation (rows o=tid, o=tid+256).
  float wc0[48], wc1[48];
#pragma unroll
  for (int a = 0; a < 48; ++a) {
    wc0[a] = wcomb[(size_t)a * OO + tid];
    wc1[a] = wcomb[(size_t)a * OO + tid + 256];
  }
  const float bc0 = bcomb[tid], bc1 = bcomb[tid + 256];

  // B1 head-dot weights (one dot per wave).
  int slot = -1;
  float wreg[16];
  float breg = 0.f;
  if (w >= NB0 && w < NBE) { int s_ = (w - NB0) * 4 + sc; if (s_ < 241) slot = s_; }
  if (slot >= 0) {
    const float* wrow = wwrT + (size_t)slot * SS;
#pragma unroll
    for (int i = 0; i < 16; ++i) wreg[i] = wrow[rl + 64 * i];
    breg = (slot < 145) ? bwv[slot] : brv[slot - 145];
  }
  // H hWout weights (one dot per wave).
  int hslot = -1;
  float wh16[16];
  if (w >= NH0) { int s_ = (w - NH0) * 4 + sc; if (s_ < 512) hslot = s_; }
  if (hslot >= 0) {
    const float* wrow = woutT + (size_t)hslot * SS;
#pragma unroll
    for (int i = 0; i < 16; ++i) wh16[i] = wrow[rl + 64 * i];
  }

  float creg = 0.f;
  float ah0 = 0.f, ah1 = 0.f, ah2 = 0.f, ah3 = 0.f;
  float m2c = 0.f;                       // D: carried ||M||^2
  float zb0 = 0.f, zb1 = 0.f;            // staged hwo+bcomb (rows tid, tid+256)
  float lab0 = 0.f, lab1 = 0.f;          // staged labels(t)

  __shared__ float pg2[2][16];
  __shared__ float errs[512];
  __shared__ float nvl[48];
  __shared__ float t1[96], t2[96], s3[49];
  __shared__ float nvln_s[48];
  __shared__ float lvs[48], lns[48];
  __shared__ float wcl[48 * 64];
  __shared__ float Mlds[2304];           // C: full row of M
  __shared__ float cred[2][4];
  __shared__ float shud[2];

  if (isD) {
    for (int i = tid; i < 48 * 64; i += NTHR)
      wcl[i] = wcomb[(size_t)(i >> 6) * OO + dbase + (i & 63)];
  }
  float hbias = 0.f;
  if (isD && tid < 64) hbias = bcomb[dbase + tid];
  if (tid < 16)
    pg2[0][tid] = pre[(size_t)(tid >> 2) * 1024 + w * 4 + (tid & 3)];
  errs[tid] = 0.f; errs[tid + 256] = 0.f;
#pragma unroll
  for (int i = 0; i < 9; ++i) Mlds[tid + i * 256] = 0.f;
  __syncthreads();

  for (int t = 0; t < TT; ++t) {
    __syncthreads();

    // ---- phase A: catch nvln, compute err locally, gate matvec, cell ----
    if (t > 0) {
      if (!isD) {
        if (tid < 48) nvl[tid] = spin1(nv2 + tid, t);
      }
      __syncthreads();
      const float* nvp = isD ? nvln_s : nvl;
      float acc0 = zb0, acc1 = zb1;
#pragma unroll
      for (int a = 0; a < 48; ++a) {
        acc0 = fmaf(nvp[a], wc0[a], acc0);
        acc1 = fmaf(nvp[a], wc1[a], acc1);
      }
      errs[tid] = 10.f * tanhf(acc0 * 0.1f) - lab0;
      errs[tid + 256] = 10.f * tanhf(acc1 * 0.1f) - lab1;
      __syncthreads();
    }
    {
      float a0 = ah0, a1 = ah1, a2 = ah2, a3 = ah3;
#pragma unroll
      for (int it = 0; it < 8; ++it) {
        float xv = errs[rl + it * 64];
        a0 = fmaf(xv, werr[it].x, a0);
        a1 = fmaf(xv, werr[it].y, a1);
        a2 = fmaf(xv, werr[it].z, a2);
        a3 = fmaf(xv, werr[it].w, a3);
      }
#pragma unroll
      for (int off = 32; off; off >>= 1) {
        a0 += __shfl_down(a0, off, 64);
        a1 += __shfl_down(a1, off, 64);
        a2 += __shfl_down(a2, off, 64);
        a3 += __shfl_down(a3, off, 64);
      }
      if (rl == 0) {
        const float* pgc = pg2[t & 1];
        float gi = a0 + pgc[0 + sc];
        float gg = a1 + pgc[4 + sc];
        float gf = a2 + pgc[8 + sc];
        float go = a3 + pgc[12 + sc];
        creg = sigm(gf + 1.f) * creg + sigm(gi) * tanhf(gg);
        float hn = sigm(go) * tanhf(creg);
        st64(hp2 + w * 4 + sc, mkpair(hn, t + 1));
      }
    }

    float hv[16];
    if (isC) {
      // ---- M rank-1 update for step t-1 (LDS, prev tick's t1) ----
      if (t > 0) {
        if (tid == 0) { shud[0] = spin1(ud2 + w, t); shud[1] = spin1(iv2, t); }
        __syncthreads();
        float uda = shud[0], ivgr = shud[1];
#pragma unroll
        for (int i = 0; i < 9; ++i) {
          int c = tid + i * 256;
          int a2 = c / 48, b2 = c - a2 * 48;
          Mlds[c] = Mlds[c] * ivgr + uda * (t1[a2] * t1[48 + b2]);
        }
      }
      // ---- h spin (precedes vp2 store: overwrite-safety) ----
      {
        u64 ph[16];
        for (;;) {
#pragma unroll
          for (int i = 0; i < 16; ++i) ph[i] = ld64(hp2 + rl + i * 64);
          int bad = 0;
#pragma unroll
          for (int i = 0; i < 16; ++i) bad |= (ptag(ph[i]) != t + 1);
          if (!bad) break;
          __builtin_amdgcn_s_sleep(1);
        }
#pragma unroll
        for (int i = 0; i < 16; ++i) hv[i] = pval(ph[i]);
      }
      __syncthreads();  // M-update done before t1/t2 overwrite
      if (tid < 192) {
        int di = (tid < 96) ? tid : (tid + 49);
        float v = spin1(wr2 + di, t + 1);
        if (tid < 96) t1[tid] = v; else t2[tid - 96] = v;
      }
      __syncthreads();
      // ---- phase C: dual matvec over full row w of M ----
      {
        float sk = 0.f, sr = 0.f;
#pragma unroll
        for (int i = 0; i < 9; ++i) {
          int c = tid + i * 256;
          int a2 = c / 48, b2 = c - a2 * 48;
          float m = Mlds[c];
          sk = fmaf(m, t1[a2] * t1[48 + b2], sk);
          sr = fmaf(m, t2[a2] * t2[48 + b2], sr);
        }
#pragma unroll
        for (int off = 32; off; off >>= 1) {
          sk += __shfl_down(sk, off, 64);
          sr += __shfl_down(sr, off, 64);
        }
        if (rl == 0) { cred[0][sc] = sk; cred[1][sc] = sr; }
        __syncthreads();
        if (tid == 0) {
          st64(vp2 + w, mkpair(cred[0][0] + cred[0][1] + cred[0][2] + cred[0][3], t + 1));
          st64(np2 + w, mkpair(cred[1][0] + cred[1][1] + cred[1][2] + cred[1][3], t + 1));
        }
      }
    } else if (isD) {
      // ---- h spin (for tail h-part; arrives before big-spin resolves) ----
      {
        u64 ph[16];
        for (;;) {
#pragma unroll
          for (int i = 0; i < 16; ++i) ph[i] = ld64(hp2 + rl + i * 64);
          int bad = 0;
#pragma unroll
          for (int i = 0; i < 16; ++i) bad |= (ptag(ph[i]) != t + 1);
          if (!bad) break;
          __builtin_amdgcn_s_sleep(1);
        }
#pragma unroll
        for (int i = 0; i < 16; ++i) hv[i] = pval(ph[i]);
      }
      // ---- big spin: 241 wr2 + 48 vp2 + 48 np2 = 337 pairs ----
      {
        const int i0 = tid, i1 = tid + 256;
        const bool h1 = (i1 < NSPIN);
        auto paddr = [&](int idx) -> const u64* {
          if (idx < 241) return wr2 + idx;
          if (idx < 289) return vp2 + (idx - 241);
          return np2 + (idx - 289);
        };
        u64 q0, q1 = 0;
        for (;;) {
          q0 = ld64(paddr(i0));
          if (h1) q1 = ld64(paddr(i1));
          int bad = (ptag(q0) != t + 1);
          if (h1) bad |= (ptag(q1) != t + 1);
          if (!bad) break;
          __builtin_amdgcn_s_sleep(1);
        }
        auto route = [&](int idx, float v) {
          if (idx < 96) t1[idx] = v;
          else if (idx < 144) s3[idx - 96] = v;
          else if (idx == 144) s3[48] = v;
          else if (idx < 241) t2[idx - 145] = v;
          else if (idx < 289) lvs[idx - 241] = v;
          else lns[idx - 289] = v;
        };
        route(i0, pval(q0));
        if (h1) route(i1, pval(q1));
      }
      __syncthreads();
      // ---- scalars (wave 0, lane a); store nvln IMMEDIATELY ----
      if (tid < 64) {
        const int a = tid;
        const bool va = a < MM;
        float lv = 0.f, d = 0.f, t1a = 0.f, t1b = 0.f, t2a = 0.f, t2b = 0.f;
        float ln = 0.f;
        if (va) {
          lv = lvs[a]; ln = lns[a];
          d = s3[a] - lv;
          t1a = t1[a]; t1b = t1[48 + a];
          t2a = t2[a]; t2b = t2[48 + a];
        }
        float beta = sigm(s3[48]);
        float sdv = va ? d * lv : 0.f;
        float sdd = va ? d * d : 0.f;
        float sk1 = va ? t1a * t1a : 0.f;
        float sk2 = va ? t1b * t1b : 0.f;
        float skn = va ? t1a * t2a : 0.f;
        float ske = va ? t1b * t2b : 0.f;
#pragma unroll
        for (int off = 32; off; off >>= 1) {
          sdv += __shfl_down(sdv, off, 64);
          sdd += __shfl_down(sdd, off, 64);
          sk1 += __shfl_down(sk1, off, 64);
          sk2 += __shfl_down(sk2, off, 64);
          skn += __shfl_down(skn, off, 64);
          ske += __shfl_down(ske, off, 64);
        }
        sdv = __shfl(sdv, 0, 64);
        sdd = __shfl(sdd, 0, 64);
        sk1 = __shfl(sk1, 0, 64);
        sk2 = __shfl(sk2, 0, 64);
        skn = __shfl(skn, 0, 64);
        ske = __shfl(ske, 0, 64);
        float n2 = m2c + 2.f * beta * sdv + beta * beta * sdd * (sk1 * sk2);
        float n2c = fmaxf(n2, 0.f);
        m2c = fminf(n2c, 1.f);
        float gam = sqrtf(n2c);
        if (gam < 1.f) gam = 1.f;
        float ivg = 1.f / gam;
        float kdr = skn * ske;
        float nv = va ? (ln + beta * d * kdr) * ivg : 0.f;
        float mean = nv, msq = nv * nv;
#pragma unroll
        for (int off = 32; off; off >>= 1) {
          mean += __shfl_down(mean, off, 64);
          msq += __shfl_down(msq, off, 64);
        }
        mean = __shfl(mean, 0, 64) * (1.f / 48.f);
        msq = __shfl(msq, 0, 64) * (1.f / 48.f);
        float rstd = rsqrtf(msq - mean * mean + 1e-5f);
        if (va) {
          float nvv = (nv - mean) * rstd;
          if (w == ND0) {
            st64(nv2 + a, mkpair(nvv, t + 1));       // the critical broadcast
            st64(ud2 + a, mkpair(beta * ivg * d, t + 1));
          }
          nvln_s[a] = nvv;
        }
        if (w == ND0 && tid == 0) st64(iv2, mkpair(ivg, t + 1));
      }
      __syncthreads();
      // ---- out slice (off critical path) ----
      if (tid < 64) {
        float hwv = spin1(hw2 + dbase + tid, t + 1);
        float acc = hwv + hbias;
#pragma unroll 8
        for (int a = 0; a < MM; ++a) acc = fmaf(nvln_s[a], wcl[a * 64 + tid], acc);
        out[(size_t)t * OO + dbase + tid] = 10.f * tanhf(acc * 0.1f);
      }
    } else {
      // ---- B1 / H: h spin, one dot per wave ----
      {
        u64 ph[16];
        for (;;) {
#pragma unroll
          for (int i = 0; i < 16; ++i) ph[i] = ld64(hp2 + rl + i * 64);
          int bad = 0;
#pragma unroll
          for (int i = 0; i < 16; ++i) bad |= (ptag(ph[i]) != t + 1);
          if (!bad) break;
          __builtin_amdgcn_s_sleep(1);
        }
#pragma unroll
        for (int i = 0; i < 16; ++i) hv[i] = pval(ph[i]);
      }
      if (slot >= 0) {
        float acc = 0.f;
#pragma unroll
        for (int i = 0; i < 16; ++i) acc = fmaf(hv[i], wreg[i], acc);
#pragma unroll
        for (int off = 32; off; off >>= 1) acc += __shfl_down(acc, off, 64);
        if (rl == 0) {
          float dv = acc + breg;
          st64(wr2 + slot, mkpair((slot == 144) ? dv : tanhf(dv), t + 1));
        }
      }
      if (hslot >= 0) {
        float acc = 0.f;
#pragma unroll
        for (int i = 0; i < 16; ++i) acc = fmaf(hv[i], wh16[i], acc);
#pragma unroll
        for (int off = 32; off; off >>= 1) acc += __shfl_down(acc, off, 64);
        if (rl == 0) st64(hw2 + hslot, mkpair(acc, t + 1));
      }
    }

    // ---- common tail: h-part precompute + next-tick staging ----
    if (t + 1 < TT) {
      float b0 = 0.f, b1 = 0.f, b2 = 0.f, b3 = 0.f;
#pragma unroll
      for (int it = 0; it < 16; ++it) {
        float xv = hv[it];
        b0 = fmaf(xv, whh[it].x, b0);
        b1 = fmaf(xv, whh[it].y, b1);
        b2 = fmaf(xv, whh[it].z, b2);
        b3 = fmaf(xv, whh[it].w, b3);
      }
      ah0 = b0; ah1 = b1; ah2 = b2; ah3 = b3;
      if (tid < 16)
        pg2[(t + 1) & 1][tid] =
            pre[(size_t)(t + 1) * NG + (tid >> 2) * 1024 + w * 4 + (tid & 3)];
      lab0 = labels[(size_t)t * OO + tid];
      lab1 = labels[(size_t)t * OO + tid + 256];
      zb0 = bc0 + spin1(hw2 + tid, t + 1);
      zb1 = bc1 + spin1(hw2 + tid + 256, t + 1);
    }
  }
}

extern "C" void kernel_launch(void* const* d_in, const int* in_sizes, int n_in,
                              void* d_out, int out_size, void* d_ws, size_t ws_size,
                              hipStream_t stream) {
  const float* inp = (const float*)d_in[0];
  const float* lab = (const float*)d_in[1];
  const float* Wl = (const float*)d_in[2];
  const float* bl = (const float*)d_in[3];
  const float* Ww = (const float*)d_in[4];
  const float* bw = (const float*)d_in[5];
  const float* Wr = (const float*)d_in[6];
  const float* br = (const float*)d_in[7];
  const float* Wrp = (const float*)d_in[8];
  const float* brp = (const float*)d_in[9];
  const float* Wo = (const float*)d_in[10];
  const float* bo = (const float*)d_in[11];
  float* ws = (float*)d_ws;
  float* outp = (float*)d_out;
  (void)in_sizes; (void)n_in; (void)out_size; (void)ws_size;

  hipMemsetAsync(d_ws, 0, (size_t)ZERO_WORDS * 4, stream);
  hipLaunchKernelGGL(build_wwrT, dim3((241 * SS + 255) / 256), dim3(256), 0, stream,
                     Ww, Wr, ws + W_WWRT);
  hipLaunchKernelGGL(build_woutT, dim3(OO * SS / 256), dim3(256), 0, stream,
                     Wo, ws + W_WOUTT);
  hipLaunchKernelGGL(repack_wl, dim3(1536 * NG / 256), dim3(256), 0, stream,
                     Wl, ws + W_WLRP);
  hipLaunchKernelGGL(wcomb_kernel, dim3(98), dim3(256), 0, stream,
                     Wrp, brp, Wo, bo, ws + W_WCOMB, ws + W_BCOMB);
  hipLaunchKernelGGL(pregate_gemm, dim3(64, 16), dim3(256), 0, stream,
                     inp, lab, Wl, bl, ws + W_PRE);
  hipLaunchKernelGGL(persistent_kernel, dim3(NWG), dim3(NTHR), 0, stream,
                     ws, lab, bw, br, outp);
}

// Round 8
// 14653.780 us; speedup vs baseline: 1.0523x; 1.0523x over previous
//
#include <hip/hip_runtime.h>
#include <math.h>

// FWMemory: T=1024 sequential ticks, persistent-kernel design.
// R8: phase A full-column per-wave decomposition (c in registers).
// R10/R11: role separation by slack; weights in VGPRs; M in LDS.
// R12: epoch-tagged dataflow {f32,epoch} atoms; all barriers deleted.
// R13 (REVERTED): err recompute on every WG + NC=48 put serial work on the
// critical path (+1.7us/tick). Structure here = R12b.
// R14: single-wave polling. In R12b all 4 waves of every WG polled the SAME
// er2 (4KB) and hp2 (8KB) lines every retry sweep -> MALL line contention.
// Now wave 0 alone polls and broadcasts via LDS (+syncthreads); poll sweep
// traffic drops 4x. In C the broadcast sync doubles as the M-update guard.

#define TT 1024
#define DD 2048
#define SS 1024
#define OO 512
#define MM 48
#define NG 4096
#define NWG 256
#define NTHR 256
#define NC 144       // phase-C WGs: 0..143
#define ND 8         // phase-D WGs: 144..151

// ---- ws layout (4-byte word offsets). Pairs are {val:u32, epoch:u32}. ----
#define W_HP2   0         // [1024] h pairs
#define W_ER2   2048      // [512] err pairs
#define W_WR2   3072      // [256] head-dot pairs (tanh'd except slot 144)
#define W_VP2   3584      // [144] voldp pairs (row*3+chunk)
#define W_NP2   3872      // [144] nrawp pairs
#define W_HW2   4160      // [512] hWout pairs
#define W_UD2   5184      // [48] beta*invg*delta pairs
#define W_IVG2  5280      // [1] invg pair
#define ZERO_WORDS 208256
#define W_PRE    208256             // [1024*4096] precomputed gates
#define W_WWRT  (W_PRE + TT*NG)     // [241*1024] W_write|W_read transposed
#define W_WOUTT (W_WWRT + 241*SS)   // [512*1024] W_out transposed
#define W_WCOMB (W_WOUTT + OO*SS)   // [48*512]  W_rproj @ W_out
#define W_BCOMB (W_WCOMB + MM*OO)   // [512]     b_rproj @ W_out + b_out
#define W_WLRP  (W_BCOMB + OO)      // [256 WGs][4 s][1536 rows] float4(4 gates)

typedef unsigned long long u64;

__device__ __forceinline__ u64 ld64(const u64* p) {
  return __hip_atomic_load(p, __ATOMIC_RELAXED, __HIP_MEMORY_SCOPE_AGENT);
}
__device__ __forceinline__ void st64(u64* p, u64 v) {
  __hip_atomic_store(p, v, __ATOMIC_RELAXED, __HIP_MEMORY_SCOPE_AGENT);
}
__device__ __forceinline__ u64 mkpair(float v, int tag) {
  union { float f; unsigned u; } c; c.f = v;
  return (u64)c.u | ((u64)(unsigned)tag << 32);
}
__device__ __forceinline__ float pval(u64 p) {
  union { unsigned u; float f; } c; c.u = (unsigned)p; return c.f;
}
__device__ __forceinline__ int ptag(u64 p) { return (int)(unsigned)(p >> 32); }
__device__ __forceinline__ float spin1(const u64* p, int tag) {
  u64 q = ld64(p);
  while (ptag(q) != tag) { __builtin_amdgcn_s_sleep(1); q = ld64(p); }
  return pval(q);
}
__device__ __forceinline__ float sigm(float x) { return 1.f / (1.f + expf(-x)); }

// ---------------- one-time prep kernels ----------------

__global__ void build_wwrT(const float* __restrict__ Ww, const float* __restrict__ Wr,
                           float* __restrict__ wwrT) {
  int id = blockIdx.x * 256 + threadIdx.x;
  if (id < 241 * SS) {
    int d = id >> 10, s = id & 1023;
    wwrT[id] = (d < 145) ? Ww[s * 145 + d] : Wr[s * 96 + (d - 145)];
  }
}

__global__ void build_woutT(const float* __restrict__ Wo, float* __restrict__ woutT) {
  int id = blockIdx.x * 256 + threadIdx.x;  // 512*1024 exact
  int o = id >> 10, s = id & 1023;
  woutT[id] = Wo[s * OO + o];
}

// Full-column layout: dst[((s*1536)+l)*4+gb] = Wl[wrow(l)][gb*1024+s].
__global__ void repack_wl(const float* __restrict__ Wl, float* __restrict__ dst) {
  int id = blockIdx.x * 256 + threadIdx.x;  // 1024*1536*4 = 1536*NG exact
  int gb = id & 3;
  int r = id >> 2;
  int l = r % 1536;
  int s = r / 1536;
  int wrow = (l < 512) ? (2048 + l) : (2560 + l);
  dst[id] = Wl[(size_t)wrow * NG + gb * 1024 + s];
}

__global__ void wcomb_kernel(const float* __restrict__ Wrp, const float* __restrict__ brp,
                             const float* __restrict__ Wo, const float* __restrict__ bo,
                             float* __restrict__ wcomb, float* __restrict__ bcomb) {
  int id = blockIdx.x * 256 + threadIdx.x;  // 49*512 exact
  int a = id >> 9, o = id & 511;
  if (a < MM) {
    float acc = 0.f;
    for (int s = 0; s < SS; ++s) acc = fmaf(Wrp[a * SS + s], Wo[s * OO + o], acc);
    wcomb[a * OO + o] = acc;
  } else if (a == MM) {
    float acc = bo[o];
    for (int s = 0; s < SS; ++s) acc = fmaf(brp[s], Wo[s * OO + o], acc);
    bcomb[o] = acc;
  }
}

// pregates[t][j] = b_lstm[j] + inp[t] @ Wl[0:2048] + labels[t-1] @ Wl[2560:3072]
__global__ __launch_bounds__(256)
void pregate_gemm(const float* __restrict__ inp, const float* __restrict__ lab,
                  const float* __restrict__ Wl, const float* __restrict__ bl,
                  float* __restrict__ pre) {
  __shared__ float As[16][65];
  __shared__ float Bs[16][64];
  const int tid = threadIdx.x;
  const int j0 = blockIdx.x * 64;
  const int t0 = blockIdx.y * 64;
  const int tx = tid & 15, ty = tid >> 4;
  float acc[4][4] = {};
  for (int kc = 0; kc < 2560; kc += 16) {
    __syncthreads();
#pragma unroll
    for (int p = 0; p < 4; ++p) {
      int id = tid + p * 256;
      int r = id >> 4, kk = id & 15;
      int t = t0 + r, k = kc + kk;
      float v;
      if (k < DD) v = inp[(size_t)t * DD + k];
      else v = (t > 0) ? lab[(size_t)(t - 1) * OO + (k - DD)] : 0.f;
      As[kk][r] = v;
      int kr = id >> 6, j = id & 63;
      int k2 = kc + kr;
      int wrow = (k2 < DD) ? k2 : (512 + k2);  // 2560+(k2-2048)
      Bs[kr][j] = Wl[(size_t)wrow * NG + j0 + j];
    }
    __syncthreads();
#pragma unroll
    for (int kk = 0; kk < 16; ++kk) {
      float av[4], bv[4];
#pragma unroll
      for (int i = 0; i < 4; ++i) av[i] = As[kk][ty * 4 + i];
#pragma unroll
      for (int i = 0; i < 4; ++i) bv[i] = Bs[kk][tx * 4 + i];
#pragma unroll
      for (int i = 0; i < 4; ++i)
#pragma unroll
        for (int jx = 0; jx < 4; ++jx) acc[i][jx] = fmaf(av[i], bv[jx], acc[i][jx]);
    }
  }
#pragma unroll
  for (int i = 0; i < 4; ++i) {
    int t = t0 + ty * 4 + i;
#pragma unroll
    for (int jx = 0; jx < 4; ++jx) {
      int j = j0 + tx * 4 + jx;
      pre[(size_t)t * NG + j] = acc[i][jx] + bl[j];
    }
  }
}

// ---------------- persistent scan kernel ----------------

__global__ __launch_bounds__(NTHR, 1)
void persistent_kernel(float* ws, const float* __restrict__ labels,
                       const float* __restrict__ bwv, const float* __restrict__ brv,
                       float* __restrict__ out) {
  u64* const hp2 = (u64*)(ws + W_HP2);
  u64* const er2 = (u64*)(ws + W_ER2);
  u64* const wr2 = (u64*)(ws + W_WR2);
  u64* const vp2 = (u64*)(ws + W_VP2);
  u64* const np2 = (u64*)(ws + W_NP2);
  u64* const hw2 = (u64*)(ws + W_HW2);
  u64* const ud2 = (u64*)(ws + W_UD2);
  u64* const iv2 = (u64*)(ws + W_IVG2);
  const float* const pre = ws + W_PRE;
  const float* const wwrT = ws + W_WWRT;
  const float* const woutT = ws + W_WOUTT;
  const float* const wcomb = ws + W_WCOMB;
  const float* const bcomb = ws + W_BCOMB;

  const int w = blockIdx.x;
  const int tid = threadIdx.x;
  const int sc = tid >> 6;   // wave id = which of this WG's 4 s-columns
  const int rl = tid & 63;   // lane
  const float4* const blk4 =
      (const float4*)(ws + W_WLRP) + (size_t)w * 6144 + (size_t)sc * 1536;

  const bool isC = (w < NC);
  const bool isD = (w >= NC && w < NC + ND);
  const int ca = w / 3, cch = w % 3;   // C role (valid when isC)
  const int dbase = (w - NC) * 64;     // D role
  const int p_ = w - (NC + ND);        // producer/H index (>=0 for w>=152)

  // Constant gate weights -> registers (once).
  float4 werr[8], whh[16];
#pragma unroll
  for (int it = 0; it < 8; ++it) werr[it] = blk4[rl + it * 64];
#pragma unroll
  for (int it = 0; it < 16; ++it) whh[it] = blk4[512 + rl + it * 64];

  // B1 producer: head-dot weight row in registers (w 152..212, 1 dot/wave).
  int slot = -1;
  float wreg[16];
  float breg = 0.f;
  if (p_ >= 0) {
    int s_ = p_ * 4 + sc;
    if (s_ < 241) slot = s_;
  }
  if (slot >= 0) {
    const float* wrow = wwrT + (size_t)slot * SS;
#pragma unroll
    for (int i = 0; i < 16; ++i) wreg[i] = wrow[rl + 64 * i];
    breg = (slot < 145) ? bwv[slot] : brv[slot - 145];
  }
  const int hslot = (p_ >= 0) ? (p_ * 4 + sc) : -1;  // 0..415 for H WGs

  float creg = 0.f;                                  // LSTM c (lane 0 per wave)
  float ah0 = 0.f, ah1 = 0.f, ah2 = 0.f, ah3 = 0.f;  // carried h-part partials
  float labr = 0.f;                                  // D: label slice (tick t)
  float m2c = 0.f;                                   // D: carried ||M||^2

  __shared__ float pg2[2][16];
  __shared__ float errs[512];          // err broadcast (wave-0 poll)
  __shared__ float hlds[1024];         // h broadcast (wave-0 poll)
  __shared__ float t1[96], t2[96], s3[49];
  __shared__ float nvln_s[MM];
  __shared__ float wcl[MM * 64];
  __shared__ float Mlds[768];          // C: this WG's fast-weight slice
  __shared__ float vps[144], nps[144], hws[64];
  __shared__ float cred[2][4];
  __shared__ float shud[2];

  if (isD) {
    for (int i = tid; i < MM * 64; i += NTHR)
      wcl[i] = wcomb[(size_t)(i >> 6) * OO + dbase + (i & 63)];
    if (tid < 64) labr = labels[dbase + tid];
  }
  float hbias = 0.f;
  if (isD && tid < 64) hbias = bcomb[dbase + tid];
  if (tid < 16)
    pg2[0][tid] = pre[(size_t)(tid >> 2) * 1024 + w * 4 + (tid & 3)];
#pragma unroll
  for (int i = 0; i < 3; ++i) Mlds[tid + i * 256] = 0.f;
  errs[tid] = 0.f; errs[tid + 256] = 0.f;
  __syncthreads();

  for (int t = 0; t < TT; ++t) {
    __syncthreads();  // LDS reuse fence between ticks (intra-WG only)

    // ---- phase A: wave 0 polls err(t-1) pairs -> LDS; matvec; cell ----
    if (t > 0) {
      if (tid < 64) {
        u64 pr[8];
        for (;;) {
#pragma unroll
          for (int i = 0; i < 8; ++i) pr[i] = ld64(er2 + tid + i * 64);
          int bad = 0;
#pragma unroll
          for (int i = 0; i < 8; ++i) bad |= (ptag(pr[i]) != t);
          if (!bad) break;
          __builtin_amdgcn_s_sleep(1);
        }
#pragma unroll
        for (int i = 0; i < 8; ++i) errs[tid + i * 64] = pval(pr[i]);
      }
      __syncthreads();
    }
    {
      float a0 = ah0, a1 = ah1, a2 = ah2, a3 = ah3;
#pragma unroll
      for (int it = 0; it < 8; ++it) {
        float xv = errs[rl + it * 64];
        a0 = fmaf(xv, werr[it].x, a0);
        a1 = fmaf(xv, werr[it].y, a1);
        a2 = fmaf(xv, werr[it].z, a2);
        a3 = fmaf(xv, werr[it].w, a3);
      }
#pragma unroll
      for (int off = 32; off; off >>= 1) {
        a0 += __shfl_down(a0, off, 64);
        a1 += __shfl_down(a1, off, 64);
        a2 += __shfl_down(a2, off, 64);
        a3 += __shfl_down(a3, off, 64);
      }
      if (rl == 0) {
        const float* pgc = pg2[t & 1];
        float gi = a0 + pgc[0 + sc];
        float gg = a1 + pgc[4 + sc];
        float gf = a2 + pgc[8 + sc];
        float go = a3 + pgc[12 + sc];
        creg = sigm(gf + 1.f) * creg + sigm(gi) * tanhf(gg);
        float hn = sigm(go) * tanhf(creg);
        st64(hp2 + w * 4 + sc, mkpair(hn, t + 1));
      }
    }

    if (isC) {
      // ---- M rank-1 update for step t-1 (LDS, prev tick's t1) ----
      if (t > 0) {
        if (tid == 0) { shud[0] = spin1(ud2 + ca, t); shud[1] = spin1(iv2, t); }
        __syncthreads();
        float uda = shud[0], ivgr = shud[1];
#pragma unroll
        for (int i = 0; i < 3; ++i) {
          int c = tid + i * 256;
          int gc = cch * 768 + c;
          int a2 = gc / 48, b2 = gc - a2 * 48;
          Mlds[c] = Mlds[c] * ivgr + uda * (t1[a2] * t1[48 + b2]);
        }
      }
      // ---- h poll (wave 0) -> LDS; sync doubles as M-update guard ----
      if (tid < 64) {
        u64 ph[16];
        for (;;) {
#pragma unroll
          for (int i = 0; i < 16; ++i) ph[i] = ld64(hp2 + tid + i * 64);
          int bad = 0;
#pragma unroll
          for (int i = 0; i < 16; ++i) bad |= (ptag(ph[i]) != t + 1);
          if (!bad) break;
          __builtin_amdgcn_s_sleep(1);
        }
#pragma unroll
        for (int i = 0; i < 16; ++i) hlds[tid + i * 64] = pval(ph[i]);
      }
      __syncthreads();  // h ready + M-update done before t1/t2 overwrite
      // ---- spin head-dot pairs -> t1/t2 ----
      if (tid < 192) {
        int di = (tid < 96) ? tid : (tid + 49);  // 145 + (tid-96)
        u64 pr = ld64(wr2 + di);
        while (ptag(pr) != t + 1) {
          __builtin_amdgcn_s_sleep(2);
          pr = ld64(wr2 + di);
        }
        if (tid < 96) t1[tid] = pval(pr); else t2[tid - 96] = pval(pr);
      }
      __syncthreads();
      // ---- phase C: dual matvec over M (LDS) ----
      {
        float sk = 0.f, sr = 0.f;
#pragma unroll
        for (int i = 0; i < 3; ++i) {
          int c = tid + i * 256;
          int gc = cch * 768 + c;
          int a2 = gc / 48, b2 = gc - a2 * 48;
          float m = Mlds[c];
          sk = fmaf(m, t1[a2] * t1[48 + b2], sk);
          sr = fmaf(m, t2[a2] * t2[48 + b2], sr);
        }
#pragma unroll
        for (int off = 32; off; off >>= 1) {
          sk += __shfl_down(sk, off, 64);
          sr += __shfl_down(sr, off, 64);
        }
        if (rl == 0) { cred[0][sc] = sk; cred[1][sc] = sr; }
        __syncthreads();
        if (tid == 0) {
          st64(vp2 + ca * 3 + cch,
               mkpair(cred[0][0] + cred[0][1] + cred[0][2] + cred[0][3], t + 1));
          st64(np2 + ca * 3 + cch,
               mkpair(cred[1][0] + cred[1][1] + cred[1][2] + cred[1][3], t + 1));
        }
      }
    } else if (isD) {
      // ---- h poll (wave 0) -> LDS ----
      if (tid < 64) {
        u64 ph[16];
        for (;;) {
#pragma unroll
          for (int i = 0; i < 16; ++i) ph[i] = ld64(hp2 + tid + i * 64);
          int bad = 0;
#pragma unroll
          for (int i = 0; i < 16; ++i) bad |= (ptag(ph[i]) != t + 1);
          if (!bad) break;
          __builtin_amdgcn_s_sleep(1);
        }
#pragma unroll
        for (int i = 0; i < 16; ++i) hlds[tid + i * 64] = pval(ph[i]);
      }
      __syncthreads();
      // ---- slack while B1/C run: h-part precompute + prefetches ----
      {
        float b0 = 0.f, b1 = 0.f, b2 = 0.f, b3 = 0.f;
#pragma unroll
        for (int it = 0; it < 16; ++it) {
          float xv = hlds[rl + it * 64];
          b0 = fmaf(xv, whh[it].x, b0);
          b1 = fmaf(xv, whh[it].y, b1);
          b2 = fmaf(xv, whh[it].z, b2);
          b3 = fmaf(xv, whh[it].w, b3);
        }
        ah0 = b0; ah1 = b1; ah2 = b2; ah3 = b3;
      }
      if (tid < 16 && t + 1 < TT)
        pg2[(t + 1) & 1][tid] =
            pre[(size_t)(t + 1) * NG + (tid >> 2) * 1024 + w * 4 + (tid & 3)];
      float labr2 = 0.f;
      if (tid < 64 && t + 1 < TT)
        labr2 = labels[(size_t)(t + 1) * OO + dbase + tid];
      // ---- big spin: 241 dots + 144 voldp + 144 nrawp + 64 hwo = 593 ----
      {
        const int i0 = tid, i1 = tid + 256, i2 = tid + 512;
        const bool h1 = (i1 < 593), h2 = (i2 < 593);
        auto paddr = [&](int idx) -> u64* {
          if (idx < 241) return wr2 + idx;
          if (idx < 385) return vp2 + (idx - 241);
          if (idx < 529) return np2 + (idx - 385);
          return hw2 + dbase + (idx - 529);
        };
        u64 q0, q1 = 0, q2 = 0;
        for (;;) {
          q0 = ld64(paddr(i0));
          if (h1) q1 = ld64(paddr(i1));
          if (h2) q2 = ld64(paddr(i2));
          int bad = (ptag(q0) != t + 1);
          if (h1) bad |= (ptag(q1) != t + 1);
          if (h2) bad |= (ptag(q2) != t + 1);
          if (!bad) break;
          __builtin_amdgcn_s_sleep(1);
        }
        auto route = [&](int idx, float v) {
          if (idx < 96) t1[idx] = v;
          else if (idx < 144) s3[idx - 96] = v;
          else if (idx == 144) s3[48] = v;
          else if (idx < 241) t2[idx - 145] = v;
          else if (idx < 385) vps[idx - 241] = v;
          else if (idx < 529) nps[idx - 385] = v;
          else hws[idx - 529] = v;
        };
        route(i0, pval(q0));
        if (h1) route(i1, pval(q1));
        if (h2) route(i2, pval(q2));
      }
      __syncthreads();
      // ---- scalars (wave 0, lane a) ----
      if (tid < 64) {
        const int a = tid;
        const bool va = a < MM;
        float lv = 0.f, d = 0.f, t1a = 0.f, t1b = 0.f, t2a = 0.f, t2b = 0.f;
        float ln = 0.f;
        if (va) {
          lv = vps[3 * a] + vps[3 * a + 1] + vps[3 * a + 2];
          ln = nps[3 * a] + nps[3 * a + 1] + nps[3 * a + 2];
          d = s3[a] - lv;
          t1a = t1[a]; t1b = t1[48 + a];
          t2a = t2[a]; t2b = t2[48 + a];
        }
        float beta = sigm(s3[48]);
        float sdv = va ? d * lv : 0.f;
        float sdd = va ? d * d : 0.f;
        float sk1 = va ? t1a * t1a : 0.f;
        float sk2 = va ? t1b * t1b : 0.f;
        float skn = va ? t1a * t2a : 0.f;
        float ske = va ? t1b * t2b : 0.f;
#pragma unroll
        for (int off = 32; off; off >>= 1) {
          sdv += __shfl_down(sdv, off, 64);
          sdd += __shfl_down(sdd, off, 64);
          sk1 += __shfl_down(sk1, off, 64);
          sk2 += __shfl_down(sk2, off, 64);
          skn += __shfl_down(skn, off, 64);
          ske += __shfl_down(ske, off, 64);
        }
        sdv = __shfl(sdv, 0, 64);
        sdd = __shfl(sdd, 0, 64);
        sk1 = __shfl(sk1, 0, 64);
        sk2 = __shfl(sk2, 0, 64);
        skn = __shfl(skn, 0, 64);
        ske = __shfl(ske, 0, 64);
        float n2 = m2c + 2.f * beta * sdv + beta * beta * sdd * (sk1 * sk2);
        float n2c = fmaxf(n2, 0.f);
        m2c = fminf(n2c, 1.f);  // ||M_normalized||^2 for next tick
        float gam = sqrtf(n2c);
        if (gam < 1.f) gam = 1.f;
        float ivg = 1.f / gam;
        float kdr = skn * ske;  // key . read_key
        float nv = va ? (ln + beta * d * kdr) * ivg : 0.f;
        float mean = nv, msq = nv * nv;
#pragma unroll
        for (int off = 32; off; off >>= 1) {
          mean += __shfl_down(mean, off, 64);
          msq += __shfl_down(msq, off, 64);
        }
        mean = __shfl(mean, 0, 64) * (1.f / 48.f);
        msq = __shfl(msq, 0, 64) * (1.f / 48.f);
        float rstd = rsqrtf(msq - mean * mean + 1e-5f);
        if (va) nvln_s[a] = (nv - mean) * rstd;
        if (w == NC) {
          if (va) st64(ud2 + a, mkpair(beta * ivg * d, t + 1));
          if (tid == 0) st64(iv2, mkpair(ivg, t + 1));
        }
      }
      __syncthreads();
      // ---- out + err slice ----
      if (tid < 64) {
        float acc = hws[tid] + hbias;
#pragma unroll 8
        for (int a = 0; a < MM; ++a) acc = fmaf(nvln_s[a], wcl[a * 64 + tid], acc);
        float y = 10.f * tanhf(acc * 0.1f);
        out[(size_t)t * OO + dbase + tid] = y;
        st64(er2 + dbase + tid, mkpair(y - labr, t + 1));
      }
      labr = labr2;
    } else {
      // ---- B1 + H (w 152..255): h poll (wave 0) -> LDS, dots ----
      if (tid < 64) {
        u64 ph[16];
        for (;;) {
#pragma unroll
          for (int i = 0; i < 16; ++i) ph[i] = ld64(hp2 + tid + i * 64);
          int bad = 0;
#pragma unroll
          for (int i = 0; i < 16; ++i) bad |= (ptag(ph[i]) != t + 1);
          if (!bad) break;
          __builtin_amdgcn_s_sleep(1);
        }
#pragma unroll
        for (int i = 0; i < 16; ++i) hlds[tid + i * 64] = pval(ph[i]);
      }
      __syncthreads();
      float hv[16];
#pragma unroll
      for (int i = 0; i < 16; ++i) hv[i] = hlds[rl + i * 64];
      if (slot >= 0) {
        float acc = 0.f;
#pragma unroll
        for (int i = 0; i < 16; ++i) acc = fmaf(hv[i], wreg[i], acc);
#pragma unroll
        for (int off = 32; off; off >>= 1) acc += __shfl_down(acc, off, 64);
        if (rl == 0) {
          float dv = acc + breg;
          st64(wr2 + slot, mkpair((slot == 144) ? dv : tanhf(dv), t + 1));
        }
      }
      // ---- hWout dots ----
      {
        const float* wrow = woutT + (size_t)hslot * SS;
        float acc = 0.f;
#pragma unroll
        for (int i = 0; i < 16; ++i)
          acc = fmaf(hv[i], wrow[rl + i * 64], acc);
#pragma unroll
        for (int off = 32; off; off >>= 1) acc += __shfl_down(acc, off, 64);
        if (rl == 0) st64(hw2 + hslot, mkpair(acc, t + 1));
        if (hslot < 96) {
          int o2 = hslot + 416;
          const float* wrow2 = woutT + (size_t)o2 * SS;
          float ac2 = 0.f;
#pragma unroll
          for (int i = 0; i < 16; ++i)
            ac2 = fmaf(hv[i], wrow2[rl + i * 64], ac2);
#pragma unroll
          for (int off = 32; off; off >>= 1) ac2 += __shfl_down(ac2, off, 64);
          if (rl == 0) st64(hw2 + o2, mkpair(ac2, t + 1));
        }
      }
    }

    // ---- common tail (C and B1/H): h-part precompute + pg prefetch ----
    if (!isD) {
      float b0 = 0.f, b1 = 0.f, b2 = 0.f, b3 = 0.f;
#pragma unroll
      for (int it = 0; it < 16; ++it) {
        float xv = hlds[rl + it * 64];
        b0 = fmaf(xv, whh[it].x, b0);
        b1 = fmaf(xv, whh[it].y, b1);
        b2 = fmaf(xv, whh[it].z, b2);
        b3 = fmaf(xv, whh[it].w, b3);
      }
      ah0 = b0; ah1 = b1; ah2 = b2; ah3 = b3;
      if (tid < 16 && t + 1 < TT)
        pg2[(t + 1) & 1][tid] =
            pre[(size_t)(t + 1) * NG + (tid >> 2) * 1024 + w * 4 + (tid & 3)];
    }
  }
}

extern "C" void kernel_launch(void* const* d_in, const int* in_sizes, int n_in,
                              void* d_out, int out_size, void* d_ws, size_t ws_size,
                              hipStream_t stream) {
  const float* inp = (const float*)d_in[0];
  const float* lab = (const float*)d_in[1];
  const float* Wl = (const float*)d_in[2];
  const float* bl = (const float*)d_in[3];
  const float* Ww = (const float*)d_in[4];
  const float* bw = (const float*)d_in[5];
  const float* Wr = (const float*)d_in[6];
  const float* br = (const float*)d_in[7];
  const float* Wrp = (const float*)d_in[8];
  const float* brp = (const float*)d_in[9];
  const float* Wo = (const float*)d_in[10];
  const float* bo = (const float*)d_in[11];
  float* ws = (float*)d_ws;
  float* outp = (float*)d_out;
  (void)in_sizes; (void)n_in; (void)out_size; (void)ws_size;

  hipMemsetAsync(d_ws, 0, (size_t)ZERO_WORDS * 4, stream);
  hipLaunchKernelGGL(build_wwrT, dim3((241 * SS + 255) / 256), dim3(256), 0, stream,
                     Ww, Wr, ws + W_WWRT);
  hipLaunchKernelGGL(build_woutT, dim3(OO * SS / 256), dim3(256), 0, stream,
                     Wo, ws + W_WOUTT);
  hipLaunchKernelGGL(repack_wl, dim3(1536 * NG / 256), dim3(256), 0, stream,
                     Wl, ws + W_WLRP);
  hipLaunchKernelGGL(wcomb_kernel, dim3(98), dim3(256), 0, stream,
                     Wrp, brp, Wo, bo, ws + W_WCOMB, ws + W_BCOMB);
  hipLaunchKernelGGL(pregate_gemm, dim3(64, 16), dim3(256), 0, stream,
                     inp, lab, Wl, bl, ws + W_PRE);
  hipLaunchKernelGGL(persistent_kernel, dim3(NWG), dim3(NTHR), 0, stream,
                     ws, lab, bw, br, outp);
}